// Round 7
// baseline (471.368 us; speedup 1.0000x reference)
//
#include <hip/hip_runtime.h>

// bf16 MFMA fragment types (gfx950): A/B = 8 bf16 (4 VGPR), C/D = 4 fp32
typedef __attribute__((ext_vector_type(8))) short bf16x8;
typedef __attribute__((ext_vector_type(4))) float f32x4;
typedef __attribute__((ext_vector_type(2))) unsigned int u32x2;
typedef __attribute__((ext_vector_type(4))) unsigned int u32x4;

#define LDSTR 136            // W1^T LDS leading dim (shorts): 128 + 8 pad
#define TPW 8                // 16-edge tiles per wave; 512 edges per block
#define BSHIFT 6             // sort key = src >> 6 (64 rows = 8 KB slice / bucket)

// f32 -> bf16 round-to-nearest-even
static __device__ __forceinline__ unsigned int pack2bf(float x, float y) {
  unsigned int ux = __builtin_bit_cast(unsigned int, x);
  ux += 0x7fffu + ((ux >> 16) & 1u);
  unsigned int uy = __builtin_bit_cast(unsigned int, y);
  uy += 0x7fffu + ((uy >> 16) & 1u);
  return (ux >> 16) | (uy & 0xffff0000u);
}
static __device__ __forceinline__ unsigned short f2bf_s(float x) {
  unsigned int ux = __builtin_bit_cast(unsigned int, x);
  ux += 0x7fffu + ((ux >> 16) & 1u);
  return (unsigned short)(ux >> 16);
}

// ---- pass 0: node table f32 -> bf16 (row = 128 B = 1 cache line) ----
__global__ __launch_bounds__(256) void cvt_nodes(const float4* __restrict__ in,
                                                 u32x2* __restrict__ out, int n4) {
  int i = blockIdx.x * 256 + threadIdx.x;
  if (i < n4) {
    float4 v = in[i];
    u32x2 p;
    p[0] = pack2bf(v.x, v.y);
    p[1] = pack2bf(v.z, v.w);
    out[i] = p;
  }
}

// ---- sort pass 1: histogram of src>>BSHIFT (LDS-aggregated) ----
__global__ __launch_bounds__(256) void hist_k(const int* __restrict__ src,
                                              int* __restrict__ hist, int E, int NB) {
  __shared__ int lh[4096];
  for (int i = threadIdx.x; i < NB; i += 256) lh[i] = 0;
  __syncthreads();
  const int stride = gridDim.x * 256;
  for (int i = blockIdx.x * 256 + threadIdx.x; i < E; i += stride)
    atomicAdd(&lh[src[i] >> BSHIFT], 1);
  __syncthreads();
  for (int i = threadIdx.x; i < NB; i += 256) {
    int v = lh[i];
    if (v) atomicAdd(&hist[i], v);
  }
}

// ---- sort pass 2: exclusive scan (single wave; NB <= 4096) ----
__global__ __launch_bounds__(64) void scan_k(const int* __restrict__ hist,
                                             int* __restrict__ ofs, int NB) {
  const int lane = threadIdx.x;
  const int C = (NB + 63) >> 6;
  const int base = lane * C;
  const int end = (base + C < NB) ? base + C : NB;
  int s = 0;
  for (int i = base; i < end; ++i) s += hist[i];
  int inc = s;
  #pragma unroll
  for (int d = 1; d < 64; d <<= 1) {
    int t = __shfl_up(inc, d);
    if (lane >= d) inc += t;
  }
  int run = inc - s;  // exclusive prefix of this lane's chunk
  for (int i = base; i < end; ++i) {
    int h = hist[i];
    ofs[i] = run;
    run += h;
  }
}

// ---- sort pass 3: scatter (src,dst,eid) int4 records into bucket order ----
__global__ __launch_bounds__(256) void scatter_k(const int* __restrict__ src,
                                                 const int* __restrict__ dst,
                                                 int* __restrict__ ofs,
                                                 int4* __restrict__ pedge, int E) {
  const int stride = gridDim.x * 256;
  for (int i = blockIdx.x * 256 + threadIdx.x; i < E; i += stride) {
    int s = src[i];
    int pos = atomicAdd(&ofs[s >> BSHIFT], 1);
    pedge[pos] = make_int4(s, dst[i], i, 0);
  }
}

// ---- main: src-sorted gather -> MFMA MLP (r4 structure, 136us codegen) ----
// Post-sort, each 512-edge block's src rows live in one ~8KB bucket slice
// (L1/L2-hot); only dst gathers still miss L2. out[] scatter-stored via eid.
__global__ __launch_bounds__(256, 3) void edge_mlp_sorted(
    const unsigned short* __restrict__ nodes_bf,  // [N,64] bf16, row = 128 B
    const int4*  __restrict__ pedge,  // [E] (src,dst,eid,0), bucket-sorted
    const float* __restrict__ W1,     // [128,64] f32 row-major
    const float* __restrict__ b1,
    const float* __restrict__ W2,     // [64]
    const float* __restrict__ b2,
    float*       __restrict__ out,    // [E]
    int E)
{
  __shared__ unsigned short ls_w1t[64 * LDSTR];
  __shared__ float ls_b1[64];
  __shared__ float ls_w2[64];

  const int tid  = threadIdx.x;
  const int wave = tid >> 6;
  const int lane = tid & 63;
  const int l15  = lane & 15;
  const int quad = lane >> 4;

  for (int i = tid; i < 64 * 128; i += 256) {
    int n = i >> 7, k = i & 127;
    ls_w1t[n * LDSTR + k] = f2bf_s(W1[k * 64 + n]);
  }
  if (tid < 64) { ls_b1[tid] = b1[tid]; ls_w2[tid] = W2[tid]; }
  __syncthreads();

  bf16x8 bfrag[4][4];
  #pragma unroll
  for (int tn = 0; tn < 4; ++tn)
    #pragma unroll
    for (int s = 0; s < 4; ++s)
      bfrag[tn][s] = *(const bf16x8*)&ls_w1t[(tn * 16 + l15) * LDSTR + s * 32 + quad * 8];

  float myb1[4], myw2[4];
  #pragma unroll
  for (int tn = 0; tn < 4; ++tn) {
    myb1[tn] = ls_b1[tn * 16 + l15];
    myw2[tn] = ls_w2[tn * 16 + l15];
  }
  const float b2v = b2[0];

  const int wave_base = blockIdx.x * (TPW * 64) + wave * (TPW * 16);
  const int qoff = quad * 16;
  const char* nb = (const char*)nodes_bf;

  // Per-tile records: coalesced int4 load of (src,dst,eid).
#define IDX(T)                                              \
  int p##T = wave_base + (T) * 16 + l15;                    \
  p##T = (p##T < E) ? p##T : (E - 1);                       \
  const int4 q##T = pedge[p##T];                            \
  const int so##T = q##T.x * 128 + qoff;                    \
  const int dd##T = q##T.y * 128 + qoff;                    \
  const int ei##T = q##T.z;

  IDX(0) IDX(1) IDX(2) IDX(3) IDX(4) IDX(5) IDX(6) IDX(7)

#define GATHER(T, A0, A1, A2, A3)                           \
  A0 = *(const bf16x8*)(nb + so##T);                        \
  A1 = *(const bf16x8*)(nb + so##T + 64);                   \
  A2 = *(const bf16x8*)(nb + dd##T);                        \
  A3 = *(const bf16x8*)(nb + dd##T + 64);

#define COMPUTE(T, A0, A1, A2, A3)                                             \
  do {                                                                         \
    f32x4 ac0 = {0.f,0.f,0.f,0.f}, ac1 = {0.f,0.f,0.f,0.f};                    \
    f32x4 ac2 = {0.f,0.f,0.f,0.f}, ac3 = {0.f,0.f,0.f,0.f};                    \
    ac0 = __builtin_amdgcn_mfma_f32_16x16x32_bf16(A0, bfrag[0][0], ac0, 0,0,0);\
    ac1 = __builtin_amdgcn_mfma_f32_16x16x32_bf16(A0, bfrag[1][0], ac1, 0,0,0);\
    ac2 = __builtin_amdgcn_mfma_f32_16x16x32_bf16(A0, bfrag[2][0], ac2, 0,0,0);\
    ac3 = __builtin_amdgcn_mfma_f32_16x16x32_bf16(A0, bfrag[3][0], ac3, 0,0,0);\
    ac0 = __builtin_amdgcn_mfma_f32_16x16x32_bf16(A1, bfrag[0][1], ac0, 0,0,0);\
    ac1 = __builtin_amdgcn_mfma_f32_16x16x32_bf16(A1, bfrag[1][1], ac1, 0,0,0);\
    ac2 = __builtin_amdgcn_mfma_f32_16x16x32_bf16(A1, bfrag[2][1], ac2, 0,0,0);\
    ac3 = __builtin_amdgcn_mfma_f32_16x16x32_bf16(A1, bfrag[3][1], ac3, 0,0,0);\
    ac0 = __builtin_amdgcn_mfma_f32_16x16x32_bf16(A2, bfrag[0][2], ac0, 0,0,0);\
    ac1 = __builtin_amdgcn_mfma_f32_16x16x32_bf16(A2, bfrag[1][2], ac1, 0,0,0);\
    ac2 = __builtin_amdgcn_mfma_f32_16x16x32_bf16(A2, bfrag[2][2], ac2, 0,0,0);\
    ac3 = __builtin_amdgcn_mfma_f32_16x16x32_bf16(A2, bfrag[3][2], ac3, 0,0,0);\
    ac0 = __builtin_amdgcn_mfma_f32_16x16x32_bf16(A3, bfrag[0][3], ac0, 0,0,0);\
    ac1 = __builtin_amdgcn_mfma_f32_16x16x32_bf16(A3, bfrag[1][3], ac1, 0,0,0);\
    ac2 = __builtin_amdgcn_mfma_f32_16x16x32_bf16(A3, bfrag[2][3], ac2, 0,0,0);\
    ac3 = __builtin_amdgcn_mfma_f32_16x16x32_bf16(A3, bfrag[3][3], ac3, 0,0,0);\
    const int tb = wave_base + (T) * 16;                                       \
    if (tb < E) {                                                              \
      _Pragma("unroll")                                                        \
      for (int r = 0; r < 4; ++r) {                                            \
        float h0 = fmaxf(ac0[r] + myb1[0], 0.f);                               \
        float h1 = fmaxf(ac1[r] + myb1[1], 0.f);                               \
        float h2 = fmaxf(ac2[r] + myb1[2], 0.f);                               \
        float h3 = fmaxf(ac3[r] + myb1[3], 0.f);                               \
        float p = h0 * myw2[0];                                                \
        p = __builtin_fmaf(h1, myw2[1], p);                                    \
        p = __builtin_fmaf(h2, myw2[2], p);                                    \
        p = __builtin_fmaf(h3, myw2[3], p);                                    \
        p += __shfl_xor(p, 1);                                                 \
        p += __shfl_xor(p, 2);                                                 \
        p += __shfl_xor(p, 4);                                                 \
        p += __shfl_xor(p, 8);                                                 \
        int eid = __shfl(ei##T, quad * 20 + r);  /* lane quad*16+(quad*4+r) */ \
        if (l15 == 0 && (tb + quad * 4 + r) < E) out[eid] = p + b2v;           \
      }                                                                        \
    }                                                                          \
  } while (0)

  bf16x8 a0, a1, a2, a3, b0, b1r, b2r, b3, c0, c1, c2, c3;

  GATHER(0, a0, a1, a2, a3)
  GATHER(1, b0, b1r, b2r, b3)
  GATHER(2, c0, c1, c2, c3)

  COMPUTE(0, a0, a1, a2, a3);   GATHER(3, a0, a1, a2, a3)
  COMPUTE(1, b0, b1r, b2r, b3); GATHER(4, b0, b1r, b2r, b3)
  COMPUTE(2, c0, c1, c2, c3);   GATHER(5, c0, c1, c2, c3)
  COMPUTE(3, a0, a1, a2, a3);   GATHER(6, a0, a1, a2, a3)
  COMPUTE(4, b0, b1r, b2r, b3); GATHER(7, b0, b1r, b2r, b3)
  COMPUTE(5, c0, c1, c2, c3);
  COMPUTE(6, a0, a1, a2, a3);
  COMPUTE(7, b0, b1r, b2r, b3);

#undef IDX
#undef GATHER
#undef COMPUTE
}

// ---- fallback A: r4 direct kernel (no sort) if ws fits only the bf16 table ----
__global__ __launch_bounds__(256, 3) void edge_mlp_direct(
    const unsigned short* __restrict__ nodes_bf,
    const int* __restrict__ src, const int* __restrict__ dst,
    const float* __restrict__ W1, const float* __restrict__ b1,
    const float* __restrict__ W2, const float* __restrict__ b2,
    float* __restrict__ out, int E)
{
  __shared__ unsigned short ls_w1t[64 * LDSTR];
  __shared__ float ls_b1[64];
  __shared__ float ls_w2[64];
  const int tid = threadIdx.x, wave = tid >> 6, lane = tid & 63;
  const int l15 = lane & 15, quad = lane >> 4;
  for (int i = tid; i < 64 * 128; i += 256) {
    int n = i >> 7, k = i & 127;
    ls_w1t[n * LDSTR + k] = f2bf_s(W1[k * 64 + n]);
  }
  if (tid < 64) { ls_b1[tid] = b1[tid]; ls_w2[tid] = W2[tid]; }
  __syncthreads();
  bf16x8 bfrag[4][4];
  #pragma unroll
  for (int tn = 0; tn < 4; ++tn)
    #pragma unroll
    for (int s = 0; s < 4; ++s)
      bfrag[tn][s] = *(const bf16x8*)&ls_w1t[(tn * 16 + l15) * LDSTR + s * 32 + quad * 8];
  float myb1[4], myw2[4];
  #pragma unroll
  for (int tn = 0; tn < 4; ++tn) { myb1[tn] = ls_b1[tn*16+l15]; myw2[tn] = ls_w2[tn*16+l15]; }
  const float b2v = b2[0];
  const int wave_base = blockIdx.x * (TPW * 64) + wave * (TPW * 16);
  const int qoff = quad * 16;
  const char* nb = (const char*)nodes_bf;
  #pragma unroll 1
  for (int t = 0; t < TPW; ++t) {
    const int tile_base = wave_base + t * 16;
    if (tile_base >= E) break;
    int e = tile_base + l15;
    const int so = src[e] * 128 + qoff;
    const int dd = dst[e] * 128 + qoff;
    bf16x8 f0 = *(const bf16x8*)(nb + so);
    bf16x8 f1 = *(const bf16x8*)(nb + so + 64);
    bf16x8 f2 = *(const bf16x8*)(nb + dd);
    bf16x8 f3 = *(const bf16x8*)(nb + dd + 64);
    f32x4 acc[4];
    #pragma unroll
    for (int tn = 0; tn < 4; ++tn) acc[tn] = (f32x4){0.f,0.f,0.f,0.f};
    #pragma unroll
    for (int tn = 0; tn < 4; ++tn) {
      acc[tn] = __builtin_amdgcn_mfma_f32_16x16x32_bf16(f0, bfrag[tn][0], acc[tn], 0,0,0);
      acc[tn] = __builtin_amdgcn_mfma_f32_16x16x32_bf16(f1, bfrag[tn][1], acc[tn], 0,0,0);
      acc[tn] = __builtin_amdgcn_mfma_f32_16x16x32_bf16(f2, bfrag[tn][2], acc[tn], 0,0,0);
      acc[tn] = __builtin_amdgcn_mfma_f32_16x16x32_bf16(f3, bfrag[tn][3], acc[tn], 0,0,0);
    }
    #pragma unroll
    for (int r = 0; r < 4; ++r) {
      float p = 0.f;
      #pragma unroll
      for (int tn = 0; tn < 4; ++tn) {
        float h = fmaxf(acc[tn][r] + myb1[tn], 0.f);
        p = __builtin_fmaf(h, myw2[tn], p);
      }
      p += __shfl_xor(p, 1); p += __shfl_xor(p, 2);
      p += __shfl_xor(p, 4); p += __shfl_xor(p, 8);
      if (l15 == 0) out[tile_base + quad * 4 + r] = p + b2v;
    }
  }
}

// ---- fallback B: f32 gathers, no workspace at all ----
static __device__ __forceinline__ bf16x8 make_afrag(float4 lo, float4 hi) {
  u32x4 p;
  p[0] = pack2bf(lo.x, lo.y);
  p[1] = pack2bf(lo.z, lo.w);
  p[2] = pack2bf(hi.x, hi.y);
  p[3] = pack2bf(hi.z, hi.w);
  return __builtin_bit_cast(bf16x8, p);
}

__global__ __launch_bounds__(256) void edge_mlp_f32(
    const float* __restrict__ nodes_emb, const int* __restrict__ src,
    const int* __restrict__ dst, const float* __restrict__ W1,
    const float* __restrict__ b1, const float* __restrict__ W2,
    const float* __restrict__ b2, float* __restrict__ out, int E)
{
  __shared__ unsigned short ls_w1t[64 * LDSTR];
  __shared__ float ls_b1[64];
  __shared__ float ls_w2[64];
  const int tid = threadIdx.x, wave = tid >> 6, lane = tid & 63;
  const int l15 = lane & 15, quad = lane >> 4;
  for (int i = tid; i < 64 * 128; i += 256) {
    int n = i >> 7, k = i & 127;
    ls_w1t[n * LDSTR + k] = f2bf_s(W1[k * 64 + n]);
  }
  if (tid < 64) { ls_b1[tid] = b1[tid]; ls_w2[tid] = W2[tid]; }
  __syncthreads();
  bf16x8 bfrag[4][4];
  #pragma unroll
  for (int tn = 0; tn < 4; ++tn)
    #pragma unroll
    for (int s = 0; s < 4; ++s)
      bfrag[tn][s] = *(const bf16x8*)&ls_w1t[(tn * 16 + l15) * LDSTR + s * 32 + quad * 8];
  float myb1[4], myw2[4];
  #pragma unroll
  for (int tn = 0; tn < 4; ++tn) { myb1[tn] = ls_b1[tn*16+l15]; myw2[tn] = ls_w2[tn*16+l15]; }
  const float b2v = b2[0];
  const int wave_base = blockIdx.x * (TPW * 64) + wave * (TPW * 16);
  #pragma unroll 1
  for (int t = 0; t < TPW; ++t) {
    const int tile_base = wave_base + t * 16;
    if (tile_base >= E) break;
    const int e = tile_base + l15;
    const int si = src[e], di = dst[e];
    const float* srow = nodes_emb + (long long)si * 64 + quad * 8;
    const float* drow = nodes_emb + (long long)di * 64 + quad * 8;
    float4 v0 = *(const float4*)(srow),      v1 = *(const float4*)(srow + 4);
    float4 v2 = *(const float4*)(srow + 32), v3 = *(const float4*)(srow + 36);
    float4 v4 = *(const float4*)(drow),      v5 = *(const float4*)(drow + 4);
    float4 v6 = *(const float4*)(drow + 32), v7 = *(const float4*)(drow + 36);
    bf16x8 afr[4] = {make_afrag(v0,v1), make_afrag(v2,v3), make_afrag(v4,v5), make_afrag(v6,v7)};
    f32x4 acc[4];
    #pragma unroll
    for (int tn = 0; tn < 4; ++tn) acc[tn] = (f32x4){0.f,0.f,0.f,0.f};
    #pragma unroll
    for (int s = 0; s < 4; ++s)
      #pragma unroll
      for (int tn = 0; tn < 4; ++tn)
        acc[tn] = __builtin_amdgcn_mfma_f32_16x16x32_bf16(afr[s], bfrag[tn][s], acc[tn], 0, 0, 0);
    #pragma unroll
    for (int r = 0; r < 4; ++r) {
      float p = 0.f;
      #pragma unroll
      for (int tn = 0; tn < 4; ++tn) {
        float h = fmaxf(acc[tn][r] + myb1[tn], 0.f);
        p = __builtin_fmaf(h, myw2[tn], p);
      }
      p += __shfl_xor(p, 1); p += __shfl_xor(p, 2);
      p += __shfl_xor(p, 4); p += __shfl_xor(p, 8);
      if (l15 == 0) out[tile_base + quad * 4 + r] = p + b2v;
    }
  }
}

extern "C" void kernel_launch(void* const* d_in, const int* in_sizes, int n_in,
                              void* d_out, int out_size, void* d_ws, size_t ws_size,
                              hipStream_t stream) {
  const float* nodes_emb = (const float*)d_in[0];
  const int*   src       = (const int*)d_in[1];
  const int*   dst       = (const int*)d_in[2];
  const float* W1        = (const float*)d_in[3];
  const float* b1        = (const float*)d_in[4];
  const float* W2        = (const float*)d_in[5];
  const float* b2        = (const float*)d_in[6];
  float* out = (float*)d_out;

  const int E = in_sizes[1];
  const int nodes_elems = in_sizes[0];               // N * 64
  const int N = nodes_elems / 64;
  const int NB = (N + ((1 << BSHIFT) - 1)) >> BSHIFT;
  const int epb = TPW * 64;                          // 512 edges / block
  const int blocks = (E + epb - 1) / epb;
  const int n4 = nodes_elems / 4;

  auto al = [](size_t x) { return (x + 255) & ~(size_t)255; };
  const size_t sz_tab  = (size_t)nodes_elems * 2;    // bf16 table
  const size_t o_hist  = al(sz_tab);
  const size_t o_ofs   = al(o_hist + (size_t)NB * 4);
  const size_t o_perm  = al(o_ofs + (size_t)NB * 4);
  const size_t need_sort = o_perm + (size_t)E * 16;  // int4 records

  char* ws = (char*)d_ws;

  if (ws_size >= need_sort && NB <= 4096) {
    unsigned short* tab = (unsigned short*)ws;
    int*  hist  = (int*)(ws + o_hist);
    int*  ofs   = (int*)(ws + o_ofs);
    int4* pedge = (int4*)(ws + o_perm);

    hipLaunchKernelGGL(cvt_nodes, dim3((n4 + 255) / 256), dim3(256), 0, stream,
                       (const float4*)nodes_emb, (u32x2*)ws, n4);
    hipMemsetAsync(hist, 0, (size_t)NB * 4, stream);
    hipLaunchKernelGGL(hist_k, dim3(256), dim3(256), 0, stream, src, hist, E, NB);
    hipLaunchKernelGGL(scan_k, dim3(1), dim3(64), 0, stream, hist, ofs, NB);
    hipLaunchKernelGGL(scatter_k, dim3(2048), dim3(256), 0, stream,
                       src, dst, ofs, pedge, E);
    hipLaunchKernelGGL(edge_mlp_sorted, dim3(blocks), dim3(256), 0, stream,
                       tab, pedge, W1, b1, W2, b2, out, E);
  } else if (ws_size >= sz_tab) {
    hipLaunchKernelGGL(cvt_nodes, dim3((n4 + 255) / 256), dim3(256), 0, stream,
                       (const float4*)nodes_emb, (u32x2*)ws, n4);
    hipLaunchKernelGGL(edge_mlp_direct, dim3(blocks), dim3(256), 0, stream,
                       (const unsigned short*)ws, src, dst, W1, b1, W2, b2, out, E);
  } else {
    hipLaunchKernelGGL(edge_mlp_f32, dim3(blocks), dim3(256), 0, stream,
                       nodes_emb, src, dst, W1, b1, W2, b2, out, E);
  }
}

// Round 8
// 206.789 us; speedup vs baseline: 2.2795x; 2.2795x over previous
//
#include <hip/hip_runtime.h>

// bf16 MFMA fragment types (gfx950): A/B = 8 bf16 (4 VGPR), C/D = 4 fp32
typedef __attribute__((ext_vector_type(8))) short bf16x8;
typedef __attribute__((ext_vector_type(4))) float f32x4;
typedef __attribute__((ext_vector_type(2))) unsigned int u32x2;
typedef __attribute__((ext_vector_type(4))) unsigned int u32x4;

#define LDSTR 136            // W1^T LDS leading dim (shorts): 128 + 8 pad
#define TPW 8                // 16-edge tiles per wave; 512 edges per block

// f32 -> bf16 round-to-nearest-even
static __device__ __forceinline__ unsigned int pack2bf(float x, float y) {
  unsigned int ux = __builtin_bit_cast(unsigned int, x);
  ux += 0x7fffu + ((ux >> 16) & 1u);
  unsigned int uy = __builtin_bit_cast(unsigned int, y);
  uy += 0x7fffu + ((uy >> 16) & 1u);
  return (ux >> 16) | (uy & 0xffff0000u);
}
static __device__ __forceinline__ unsigned short f2bf_s(float x) {
  unsigned int ux = __builtin_bit_cast(unsigned int, x);
  ux += 0x7fffu + ((ux >> 16) & 1u);
  return (unsigned short)(ux >> 16);
}

// ---- pass 0: node table f32 -> bf16 (row = 128 B = 1 cache line) ----
__global__ __launch_bounds__(256) void cvt_nodes(const float4* __restrict__ in,
                                                 u32x2* __restrict__ out, int n4) {
  int i = blockIdx.x * 256 + threadIdx.x;
  if (i < n4) {
    float4 v = in[i];
    u32x2 p;
    p[0] = pack2bf(v.x, v.y);
    p[1] = pack2bf(v.z, v.w);
    out[i] = p;
  }
}

// ---- main: adjacent-lane-contiguous gather -> LDS transpose -> MFMA ----
// r1..r7 evidence: the cap is divergent-address lane-request throughput in
// the vector-memory path (depth/DMA/locality all no-ops; f32's 2x lanes =
// 1.65x time). Old gathers put DIFFERENT rows in ADJACENT lanes (no merge).
// Here 8 consecutive lanes fetch one contiguous 128-B row (merge-friendly),
// then a per-wave XOR-swizzled LDS buffer transposes to MFMA A-layout.
__global__ __launch_bounds__(256, 3) void edge_mlp_bf16(
    const unsigned short* __restrict__ nodes_bf,  // [N,64] bf16, row = 128 B
    const int*   __restrict__ src,
    const int*   __restrict__ dst,
    const float* __restrict__ W1,   // [128,64] f32 row-major
    const float* __restrict__ b1,
    const float* __restrict__ W2,   // [64]
    const float* __restrict__ b2,
    float*       __restrict__ out,  // [E]
    int E)
{
  __shared__ unsigned short ls_w1t[64 * LDSTR];
  __shared__ float ls_b1[64];
  __shared__ float ls_w2[64];
  __shared__ unsigned short stage[4 * 4096];  // per wave: 2 bufs x 2048 shorts (4 KB)

  const int tid  = threadIdx.x;
  const int wave = tid >> 6;
  const int lane = tid & 63;
  const int l15  = lane & 15;
  const int quad = lane >> 4;

  for (int i = tid; i < 64 * 128; i += 256) {
    int n = i >> 7, k = i & 127;
    ls_w1t[n * LDSTR + k] = f2bf_s(W1[k * 64 + n]);
  }
  if (tid < 64) { ls_b1[tid] = b1[tid]; ls_w2[tid] = W2[tid]; }
  __syncthreads();

  // bfrag[tn][s] = W1T[n=tn*16+l15][k=s*32+quad*8 .. +7]
  bf16x8 bfrag[4][4];
  #pragma unroll
  for (int tn = 0; tn < 4; ++tn)
    #pragma unroll
    for (int s = 0; s < 4; ++s)
      bfrag[tn][s] = *(const bf16x8*)&ls_w1t[(tn * 16 + l15) * LDSTR + s * 32 + quad * 8];

  float myb1[4], myw2[4];
  #pragma unroll
  for (int tn = 0; tn < 4; ++tn) {
    myb1[tn] = ls_b1[tn * 16 + l15];
    myw2[tn] = ls_w2[tn * 16 + l15];
  }
  const float b2v = b2[0];

  const int wave_base = blockIdx.x * (TPW * 64) + wave * (TPW * 16);
  const char* nb = (const char*)nodes_bf;
  unsigned short* lws = stage + wave * 4096;   // this wave's 2 x 2048-short bufs

  const int sub   = lane >> 3;                 // row-in-group 0..7
  const int lo16  = (lane & 7) * 16;           // byte sliver within row
  // write slot (shorts): row field + XOR-swizzled sliver (conflict-free)
  const int wbase = sub * 64 + (((lane & 7) ^ sub) * 8);
  // read addrs (shorts): fragment slivers quad and quad+4 of row l15
  const int ra = l15 * 64 + ((quad ^ (l15 & 7)) * 8);
  const int rb = l15 * 64 + (((quad + 4) ^ (l15 & 7)) * 8);

  // Per-tile row byte-offsets (held by lanes 0..15; clamped)
#define IDX(T)                                              \
  int e##T = wave_base + (T) * 16 + l15;                    \
  e##T = (e##T < E) ? e##T : 0;                             \
  const int so##T = src[e##T] * 128;                        \
  const int dd##T = dst[e##T] * 128;

  IDX(0) IDX(1) IDX(2) IDX(3) IDX(4) IDX(5) IDX(6) IDX(7)

  bf16x8 A0, A1, A2, A3;      // gather regs (1-tile lookahead, r4-proven)
  bf16x8 f0, f1, f2, f3;      // MFMA A-fragments

  // Contiguous gather: 8 consecutive lanes cover one full 128-B row.
  // A0: src rows 0-7, A1: src rows 8-15, A2/A3: dst rows.
#define GATHERC(T)                                          \
  {                                                         \
    int r0 = __shfl(so##T, sub);                            \
    int r1 = __shfl(so##T, sub + 8);                        \
    int r2 = __shfl(dd##T, sub);                            \
    int r3 = __shfl(dd##T, sub + 8);                        \
    A0 = *(const bf16x8*)(nb + r0 + lo16);                  \
    A1 = *(const bf16x8*)(nb + r1 + lo16);                  \
    A2 = *(const bf16x8*)(nb + r2 + lo16);                  \
    A3 = *(const bf16x8*)(nb + r3 + lo16);                  \
  }

  // Stage to LDS buffer P: regions of 512 shorts per 8-row group.
#define WRITEQ(P)                                           \
  {                                                         \
    unsigned short* wb_ = lws + (P) * 2048 + wbase;         \
    *(bf16x8*)(wb_)        = A0;                            \
    *(bf16x8*)(wb_ + 512)  = A1;                            \
    *(bf16x8*)(wb_ + 1024) = A2;                            \
    *(bf16x8*)(wb_ + 1536) = A3;                            \
  }

  // Fragments: src row l15 (slivers quad, quad+4), dst row l15 (+1024)
#define READF(P)                                            \
  {                                                         \
    const unsigned short* rb_ = lws + (P) * 2048;           \
    f0 = *(const bf16x8*)(rb_ + ra);                        \
    f1 = *(const bf16x8*)(rb_ + rb);                        \
    f2 = *(const bf16x8*)(rb_ + 1024 + ra);                 \
    f3 = *(const bf16x8*)(rb_ + 1024 + rb);                 \
  }

#define COMPUTE(T)                                                             \
  do {                                                                         \
    f32x4 ac0 = {0.f,0.f,0.f,0.f}, ac1 = {0.f,0.f,0.f,0.f};                    \
    f32x4 ac2 = {0.f,0.f,0.f,0.f}, ac3 = {0.f,0.f,0.f,0.f};                    \
    ac0 = __builtin_amdgcn_mfma_f32_16x16x32_bf16(f0, bfrag[0][0], ac0, 0,0,0);\
    ac1 = __builtin_amdgcn_mfma_f32_16x16x32_bf16(f0, bfrag[1][0], ac1, 0,0,0);\
    ac2 = __builtin_amdgcn_mfma_f32_16x16x32_bf16(f0, bfrag[2][0], ac2, 0,0,0);\
    ac3 = __builtin_amdgcn_mfma_f32_16x16x32_bf16(f0, bfrag[3][0], ac3, 0,0,0);\
    ac0 = __builtin_amdgcn_mfma_f32_16x16x32_bf16(f1, bfrag[0][1], ac0, 0,0,0);\
    ac1 = __builtin_amdgcn_mfma_f32_16x16x32_bf16(f1, bfrag[1][1], ac1, 0,0,0);\
    ac2 = __builtin_amdgcn_mfma_f32_16x16x32_bf16(f1, bfrag[2][1], ac2, 0,0,0);\
    ac3 = __builtin_amdgcn_mfma_f32_16x16x32_bf16(f1, bfrag[3][1], ac3, 0,0,0);\
    ac0 = __builtin_amdgcn_mfma_f32_16x16x32_bf16(f2, bfrag[0][2], ac0, 0,0,0);\
    ac1 = __builtin_amdgcn_mfma_f32_16x16x32_bf16(f2, bfrag[1][2], ac1, 0,0,0);\
    ac2 = __builtin_amdgcn_mfma_f32_16x16x32_bf16(f2, bfrag[2][2], ac2, 0,0,0);\
    ac3 = __builtin_amdgcn_mfma_f32_16x16x32_bf16(f2, bfrag[3][2], ac3, 0,0,0);\
    ac0 = __builtin_amdgcn_mfma_f32_16x16x32_bf16(f3, bfrag[0][3], ac0, 0,0,0);\
    ac1 = __builtin_amdgcn_mfma_f32_16x16x32_bf16(f3, bfrag[1][3], ac1, 0,0,0);\
    ac2 = __builtin_amdgcn_mfma_f32_16x16x32_bf16(f3, bfrag[2][3], ac2, 0,0,0);\
    ac3 = __builtin_amdgcn_mfma_f32_16x16x32_bf16(f3, bfrag[3][3], ac3, 0,0,0);\
    const int tb = wave_base + (T) * 16;                                       \
    if (tb < E) {                                                              \
      _Pragma("unroll")                                                        \
      for (int r = 0; r < 4; ++r) {                                            \
        float h0 = fmaxf(ac0[r] + myb1[0], 0.f);                               \
        float h1 = fmaxf(ac1[r] + myb1[1], 0.f);                               \
        float h2 = fmaxf(ac2[r] + myb1[2], 0.f);                               \
        float h3 = fmaxf(ac3[r] + myb1[3], 0.f);                               \
        float p = h0 * myw2[0];                                                \
        p = __builtin_fmaf(h1, myw2[1], p);                                    \
        p = __builtin_fmaf(h2, myw2[2], p);                                    \
        p = __builtin_fmaf(h3, myw2[3], p);                                    \
        p += __shfl_xor(p, 1);                                                 \
        p += __shfl_xor(p, 2);                                                 \
        p += __shfl_xor(p, 4);                                                 \
        p += __shfl_xor(p, 8);                                                 \
        if (l15 == 0) out[tb + quad * 4 + r] = p + b2v;                        \
      }                                                                        \
    }                                                                          \
  } while (0)

  // Preamble: tile0 staged, tile1 in flight.
  GATHERC(0);
  WRITEQ(0);
  GATHERC(1);

  // iter t: read tile t (buf t&1), stage tile t+1 (buf (t+1)&1, waits its
  // gather), launch gather t+2, compute tile t.
  READF(0); WRITEQ(1); GATHERC(2); COMPUTE(0);
  READF(1); WRITEQ(0); GATHERC(3); COMPUTE(1);
  READF(0); WRITEQ(1); GATHERC(4); COMPUTE(2);
  READF(1); WRITEQ(0); GATHERC(5); COMPUTE(3);
  READF(0); WRITEQ(1); GATHERC(6); COMPUTE(4);
  READF(1); WRITEQ(0); GATHERC(7); COMPUTE(5);
  READF(0); WRITEQ(1);             COMPUTE(6);
  READF(1);                        COMPUTE(7);

#undef IDX
#undef GATHERC
#undef WRITEQ
#undef READF
#undef COMPUTE
}

// ---- fallback: f32 gathers (no workspace) ----
static __device__ __forceinline__ bf16x8 make_afrag(float4 lo, float4 hi) {
  u32x4 p;
  p[0] = pack2bf(lo.x, lo.y);
  p[1] = pack2bf(lo.z, lo.w);
  p[2] = pack2bf(hi.x, hi.y);
  p[3] = pack2bf(hi.z, hi.w);
  return __builtin_bit_cast(bf16x8, p);
}

__global__ __launch_bounds__(256) void edge_mlp_f32(
    const float* __restrict__ nodes_emb, const int* __restrict__ src,
    const int* __restrict__ dst, const float* __restrict__ W1,
    const float* __restrict__ b1, const float* __restrict__ W2,
    const float* __restrict__ b2, float* __restrict__ out, int E)
{
  __shared__ unsigned short ls_w1t[64 * LDSTR];
  __shared__ float ls_b1[64];
  __shared__ float ls_w2[64];
  const int tid = threadIdx.x, wave = tid >> 6, lane = tid & 63;
  const int l15 = lane & 15, quad = lane >> 4;
  for (int i = tid; i < 64 * 128; i += 256) {
    int n = i >> 7, k = i & 127;
    ls_w1t[n * LDSTR + k] = f2bf_s(W1[k * 64 + n]);
  }
  if (tid < 64) { ls_b1[tid] = b1[tid]; ls_w2[tid] = W2[tid]; }
  __syncthreads();
  bf16x8 bfrag[4][4];
  #pragma unroll
  for (int tn = 0; tn < 4; ++tn)
    #pragma unroll
    for (int s = 0; s < 4; ++s)
      bfrag[tn][s] = *(const bf16x8*)&ls_w1t[(tn * 16 + l15) * LDSTR + s * 32 + quad * 8];
  float myb1[4], myw2[4];
  #pragma unroll
  for (int tn = 0; tn < 4; ++tn) { myb1[tn] = ls_b1[tn*16+l15]; myw2[tn] = ls_w2[tn*16+l15]; }
  const float b2v = b2[0];
  const int wave_base = blockIdx.x * (TPW * 64) + wave * (TPW * 16);
  #pragma unroll 1
  for (int t = 0; t < TPW; ++t) {
    const int tile_base = wave_base + t * 16;
    if (tile_base >= E) break;
    const int e = tile_base + l15;
    const int si = src[e], di = dst[e];
    const float* srow = nodes_emb + (long long)si * 64 + quad * 8;
    const float* drow = nodes_emb + (long long)di * 64 + quad * 8;
    float4 v0 = *(const float4*)(srow),      v1 = *(const float4*)(srow + 4);
    float4 v2 = *(const float4*)(srow + 32), v3 = *(const float4*)(srow + 36);
    float4 v4 = *(const float4*)(drow),      v5 = *(const float4*)(drow + 4);
    float4 v6 = *(const float4*)(drow + 32), v7 = *(const float4*)(drow + 36);
    bf16x8 afr[4] = {make_afrag(v0,v1), make_afrag(v2,v3), make_afrag(v4,v5), make_afrag(v6,v7)};
    f32x4 acc[4];
    #pragma unroll
    for (int tn = 0; tn < 4; ++tn) acc[tn] = (f32x4){0.f,0.f,0.f,0.f};
    #pragma unroll
    for (int s = 0; s < 4; ++s)
      #pragma unroll
      for (int tn = 0; tn < 4; ++tn)
        acc[tn] = __builtin_amdgcn_mfma_f32_16x16x32_bf16(afr[s], bfrag[tn][s], acc[tn], 0, 0, 0);
    #pragma unroll
    for (int r = 0; r < 4; ++r) {
      float p = 0.f;
      #pragma unroll
      for (int tn = 0; tn < 4; ++tn) {
        float h = fmaxf(acc[tn][r] + myb1[tn], 0.f);
        p = __builtin_fmaf(h, myw2[tn], p);
      }
      p += __shfl_xor(p, 1); p += __shfl_xor(p, 2);
      p += __shfl_xor(p, 4); p += __shfl_xor(p, 8);
      if (l15 == 0) out[tile_base + quad * 4 + r] = p + b2v;
    }
  }
}

extern "C" void kernel_launch(void* const* d_in, const int* in_sizes, int n_in,
                              void* d_out, int out_size, void* d_ws, size_t ws_size,
                              hipStream_t stream) {
  const float* nodes_emb = (const float*)d_in[0];
  const int*   src       = (const int*)d_in[1];
  const int*   dst       = (const int*)d_in[2];
  const float* W1        = (const float*)d_in[3];
  const float* b1        = (const float*)d_in[4];
  const float* W2        = (const float*)d_in[5];
  const float* b2        = (const float*)d_in[6];
  float* out = (float*)d_out;

  const int E = in_sizes[1];
  const int nodes_elems = in_sizes[0];               // N * 64
  const int epb = TPW * 64;                          // 512 edges / block
  const int blocks = (E + epb - 1) / epb;
  const int n4 = nodes_elems / 4;
  const size_t need = (size_t)nodes_elems * 2;       // bf16 table bytes

  if (ws_size >= need) {
    hipLaunchKernelGGL(cvt_nodes, dim3((n4 + 255) / 256), dim3(256), 0, stream,
                       (const float4*)nodes_emb, (u32x2*)d_ws, n4);
    hipLaunchKernelGGL(edge_mlp_bf16, dim3(blocks), dim3(256), 0, stream,
                       (const unsigned short*)d_ws, src, dst, W1, b1, W2, b2, out, E);
  } else {
    hipLaunchKernelGGL(edge_mlp_f32, dim3(blocks), dim3(256), 0, stream,
                       nodes_emb, src, dst, W1, b1, W2, b2, out, E);
  }
}

// Round 9
// 203.875 us; speedup vs baseline: 2.3120x; 1.0143x over previous
//
#include <hip/hip_runtime.h>

// bf16 MFMA fragment types (gfx950): A/B = 8 bf16 (4 VGPR), C/D = 4 fp32
typedef __attribute__((ext_vector_type(8))) short bf16x8;
typedef __attribute__((ext_vector_type(4))) float f32x4;
typedef __attribute__((ext_vector_type(4))) unsigned int u32x4;

#define LDSTR 136            // W1^T LDS leading dim (shorts): 128 + 8 pad
#define TPW 8                // (fallback) 16-edge tiles per wave

// f32 -> bf16 round-to-nearest-even
static __device__ __forceinline__ unsigned int pack2bf(float x, float y) {
  unsigned int ux = __builtin_bit_cast(unsigned int, x);
  ux += 0x7fffu + ((ux >> 16) & 1u);
  unsigned int uy = __builtin_bit_cast(unsigned int, y);
  uy += 0x7fffu + ((uy >> 16) & 1u);
  return (ux >> 16) | (uy & 0xffff0000u);
}
static __device__ __forceinline__ unsigned short f2bf_s(float x) {
  unsigned int ux = __builtin_bit_cast(unsigned int, x);
  ux += 0x7fffu + ((ux >> 16) & 1u);
  return (unsigned short)(ux >> 16);
}
static __device__ __forceinline__ bf16x8 make_afrag(float4 lo, float4 hi) {
  u32x4 p;
  p[0] = pack2bf(lo.x, lo.y);
  p[1] = pack2bf(lo.z, lo.w);
  p[2] = pack2bf(hi.x, hi.y);
  p[3] = pack2bf(hi.z, hi.w);
  return __builtin_bit_cast(bf16x8, p);
}

// ---- pass 0: per-node projections  P = emb @ W1[0:64], Q = emb @ W1[64:128]
// (bf16 rows, 128 B each). Moves ALL W1 MFMAs out of the edge loop: per edge
// h = relu(P[src]+Q[dst]+b1), logit = h.W2 + b2.
__global__ __launch_bounds__(256) void node_proj(
    const float* __restrict__ emb,   // [N,64] f32
    const float* __restrict__ W1,    // [128,64] f32 row-major
    unsigned short* __restrict__ P,  // [N,64] bf16
    unsigned short* __restrict__ Q,  // [N,64] bf16
    int N)
{
  __shared__ unsigned short ls_w1t[64 * LDSTR];   // W1^T [n][k]
  const int tid  = threadIdx.x;
  const int wave = tid >> 6;
  const int lane = tid & 63;
  const int l15  = lane & 15;
  const int quad = lane >> 4;

  for (int i = tid; i < 64 * 128; i += 256) {
    int n = i >> 7, k = i & 127;
    ls_w1t[n * LDSTR + k] = f2bf_s(W1[k * 64 + n]);
  }
  __syncthreads();

  // bfragP[tn][s]: k = s*32+quad*8 (W1 top half); bfragQ: k = 64 + ...
  bf16x8 bfragP[4][2], bfragQ[4][2];
  #pragma unroll
  for (int tn = 0; tn < 4; ++tn)
    #pragma unroll
    for (int s = 0; s < 2; ++s) {
      bfragP[tn][s] = *(const bf16x8*)&ls_w1t[(tn * 16 + l15) * LDSTR + s * 32 + quad * 8];
      bfragQ[tn][s] = *(const bf16x8*)&ls_w1t[(tn * 16 + l15) * LDSTR + 64 + s * 32 + quad * 8];
    }

  const int tile = blockIdx.x * 4 + wave;         // 16 nodes per tile
  const int base = tile * 16;
  if (base >= N) return;

  // A-frags: emb rows base+l15, k-slivers s*32+quad*8 (dense 16x256B region)
  bf16x8 afr[2];
  {
    int node = base + l15;
    node = (node < N) ? node : N - 1;
    const float* rp = emb + (long long)node * 64 + quad * 8;
    afr[0] = make_afrag(*(const float4*)(rp),      *(const float4*)(rp + 4));
    afr[1] = make_afrag(*(const float4*)(rp + 32), *(const float4*)(rp + 36));
  }

  f32x4 aP[4], aQ[4];
  #pragma unroll
  for (int tn = 0; tn < 4; ++tn) { aP[tn] = (f32x4){0,0,0,0}; aQ[tn] = (f32x4){0,0,0,0}; }
  #pragma unroll
  for (int s = 0; s < 2; ++s)
    #pragma unroll
    for (int tn = 0; tn < 4; ++tn) {
      aP[tn] = __builtin_amdgcn_mfma_f32_16x16x32_bf16(afr[s], bfragP[tn][s], aP[tn], 0, 0, 0);
      aQ[tn] = __builtin_amdgcn_mfma_f32_16x16x32_bf16(afr[s], bfragQ[tn][s], aQ[tn], 0, 0, 0);
    }

  // C layout: col = l15 (channel within tn), row = quad*4 + r (node)
  #pragma unroll
  for (int r = 0; r < 4; ++r) {
    const int m = base + quad * 4 + r;
    if (m < N) {
      #pragma unroll
      for (int tn = 0; tn < 4; ++tn) {
        P[(long long)m * 64 + tn * 16 + l15] = f2bf_s(aP[tn][r]);
        Q[(long long)m * 64 + tn * 16 + l15] = f2bf_s(aQ[tn][r]);
      }
    }
  }
}

// ---- main: pure streaming edge scorer. 8 lanes per edge; each lane holds
// 8 channels. Zero LDS, zero MFMA, tiny VGPR -> max occupancy. Gathers are
// adjacent-lane-contiguous (8 lanes = one full 128-B row), same segment
// profile as r8 but with no per-tile serialization.
__global__ __launch_bounds__(256) void edge_score(
    const unsigned short* __restrict__ P,   // [N,64] bf16
    const unsigned short* __restrict__ Q,   // [N,64] bf16
    const int*   __restrict__ src,
    const int*   __restrict__ dst,
    const float* __restrict__ b1,    // [64]
    const float* __restrict__ W2,    // [64]
    const float* __restrict__ b2,
    float*       __restrict__ out,   // [E]
    int E)
{
  const int tid  = blockIdx.x * 256 + threadIdx.x;
  const int lane = threadIdx.x & 63;
  const int s    = lane & 7;          // sliver within row (8 bf16 = 16 B)
  const int g    = lane >> 3;         // edge-group within wave (0..7)
  const int wid  = tid >> 6;          // global wave id
  const int nwav = gridDim.x * 4;

  // Per-lane channel constants: channels s*8 .. s*8+7
  float b1v[8], w2v[8];
  {
    const float4 ba = *(const float4*)(b1 + s * 8);
    const float4 bb = *(const float4*)(b1 + s * 8 + 4);
    const float4 wa = *(const float4*)(W2 + s * 8);
    const float4 wb = *(const float4*)(W2 + s * 8 + 4);
    b1v[0]=ba.x; b1v[1]=ba.y; b1v[2]=ba.z; b1v[3]=ba.w;
    b1v[4]=bb.x; b1v[5]=bb.y; b1v[6]=bb.z; b1v[7]=bb.w;
    w2v[0]=wa.x; w2v[1]=wa.y; w2v[2]=wa.z; w2v[3]=wa.w;
    w2v[4]=wb.x; w2v[5]=wb.y; w2v[6]=wb.z; w2v[7]=wb.w;
  }
  const float b2v = b2[0];
  const int so16 = s * 8;             // short offset of this lane's sliver

  // one dot-8 with bf16 unpack (hi/lo 16-bit fields -> f32 via bit ops)
#define DOT8(PV, QV, ACC)                                                     \
  {                                                                           \
    u32x4 pu = __builtin_bit_cast(u32x4, PV);                                 \
    u32x4 qu = __builtin_bit_cast(u32x4, QV);                                 \
    _Pragma("unroll")                                                         \
    for (int i = 0; i < 4; ++i) {                                             \
      float pl = __builtin_bit_cast(float, pu[i] << 16);                      \
      float ph = __builtin_bit_cast(float, pu[i] & 0xffff0000u);              \
      float ql = __builtin_bit_cast(float, qu[i] << 16);                      \
      float qh = __builtin_bit_cast(float, qu[i] & 0xffff0000u);              \
      float h0 = fmaxf(pl + ql + b1v[2 * i], 0.f);                            \
      float h1 = fmaxf(ph + qh + b1v[2 * i + 1], 0.f);                        \
      ACC = __builtin_fmaf(h0, w2v[2 * i], ACC);                              \
      ACC = __builtin_fmaf(h1, w2v[2 * i + 1], ACC);                          \
    }                                                                         \
  }

  // 16 edges per wave per iteration (two independent 8-edge chunks in flight)
  const int step = nwav * 16;
  for (int e0 = wid * 16; e0 < E; e0 += step) {
    int eA = e0 + g;
    int eB = e0 + 8 + g;
    const int eAc = (eA < E) ? eA : (E - 1);
    const int eBc = (eB < E) ? eB : (E - 1);
    const int siA = src[eAc], diA = dst[eAc];
    const int siB = src[eBc], diB = dst[eBc];

    const bf16x8 pvA = *(const bf16x8*)(P + (long long)siA * 64 + so16);
    const bf16x8 qvA = *(const bf16x8*)(Q + (long long)diA * 64 + so16);
    const bf16x8 pvB = *(const bf16x8*)(P + (long long)siB * 64 + so16);
    const bf16x8 qvB = *(const bf16x8*)(Q + (long long)diB * 64 + so16);

    float accA = 0.f, accB = 0.f;
    DOT8(pvA, qvA, accA);
    DOT8(pvB, qvB, accB);

    // reduce over the 8 lanes of the group
    accA += __shfl_xor(accA, 1); accB += __shfl_xor(accB, 1);
    accA += __shfl_xor(accA, 2); accB += __shfl_xor(accB, 2);
    accA += __shfl_xor(accA, 4); accB += __shfl_xor(accB, 4);

    if (s == 0) {
      if (eA < E) out[eA] = accA + b2v;
      if (eB < E) out[eB] = accB + b2v;
    }
  }
#undef DOT8
}

// ---- fallback: f32 gathers + MFMA (no workspace) ----
__global__ __launch_bounds__(256) void edge_mlp_f32(
    const float* __restrict__ nodes_emb, const int* __restrict__ src,
    const int* __restrict__ dst, const float* __restrict__ W1,
    const float* __restrict__ b1, const float* __restrict__ W2,
    const float* __restrict__ b2, float* __restrict__ out, int E)
{
  __shared__ unsigned short ls_w1t[64 * LDSTR];
  __shared__ float ls_b1[64];
  __shared__ float ls_w2[64];
  const int tid = threadIdx.x, wave = tid >> 6, lane = tid & 63;
  const int l15 = lane & 15, quad = lane >> 4;
  for (int i = tid; i < 64 * 128; i += 256) {
    int n = i >> 7, k = i & 127;
    ls_w1t[n * LDSTR + k] = f2bf_s(W1[k * 64 + n]);
  }
  if (tid < 64) { ls_b1[tid] = b1[tid]; ls_w2[tid] = W2[tid]; }
  __syncthreads();
  bf16x8 bfrag[4][4];
  #pragma unroll
  for (int tn = 0; tn < 4; ++tn)
    #pragma unroll
    for (int s = 0; s < 4; ++s)
      bfrag[tn][s] = *(const bf16x8*)&ls_w1t[(tn * 16 + l15) * LDSTR + s * 32 + quad * 8];
  float myb1[4], myw2[4];
  #pragma unroll
  for (int tn = 0; tn < 4; ++tn) { myb1[tn] = ls_b1[tn*16+l15]; myw2[tn] = ls_w2[tn*16+l15]; }
  const float b2v = b2[0];
  const int wave_base = blockIdx.x * (TPW * 64) + wave * (TPW * 16);
  #pragma unroll 1
  for (int t = 0; t < TPW; ++t) {
    const int tile_base = wave_base + t * 16;
    if (tile_base >= E) break;
    const int e = tile_base + l15;
    const int si = src[e], di = dst[e];
    const float* srow = nodes_emb + (long long)si * 64 + quad * 8;
    const float* drow = nodes_emb + (long long)di * 64 + quad * 8;
    float4 v0 = *(const float4*)(srow),      v1 = *(const float4*)(srow + 4);
    float4 v2 = *(const float4*)(srow + 32), v3 = *(const float4*)(srow + 36);
    float4 v4 = *(const float4*)(drow),      v5 = *(const float4*)(drow + 4);
    float4 v6 = *(const float4*)(drow + 32), v7 = *(const float4*)(drow + 36);
    bf16x8 afr[4] = {make_afrag(v0,v1), make_afrag(v2,v3), make_afrag(v4,v5), make_afrag(v6,v7)};
    f32x4 acc[4];
    #pragma unroll
    for (int tn = 0; tn < 4; ++tn) acc[tn] = (f32x4){0.f,0.f,0.f,0.f};
    #pragma unroll
    for (int s = 0; s < 4; ++s)
      #pragma unroll
      for (int tn = 0; tn < 4; ++tn)
        acc[tn] = __builtin_amdgcn_mfma_f32_16x16x32_bf16(afr[s], bfrag[tn][s], acc[tn], 0, 0, 0);
    #pragma unroll
    for (int r = 0; r < 4; ++r) {
      float p = 0.f;
      #pragma unroll
      for (int tn = 0; tn < 4; ++tn) {
        float h = fmaxf(acc[tn][r] + myb1[tn], 0.f);
        p = __builtin_fmaf(h, myw2[tn], p);
      }
      p += __shfl_xor(p, 1); p += __shfl_xor(p, 2);
      p += __shfl_xor(p, 4); p += __shfl_xor(p, 8);
      if (l15 == 0) out[tile_base + quad * 4 + r] = p + b2v;
    }
  }
}

extern "C" void kernel_launch(void* const* d_in, const int* in_sizes, int n_in,
                              void* d_out, int out_size, void* d_ws, size_t ws_size,
                              hipStream_t stream) {
  const float* nodes_emb = (const float*)d_in[0];
  const int*   src       = (const int*)d_in[1];
  const int*   dst       = (const int*)d_in[2];
  const float* W1        = (const float*)d_in[3];
  const float* b1        = (const float*)d_in[4];
  const float* W2        = (const float*)d_in[5];
  const float* b2        = (const float*)d_in[6];
  float* out = (float*)d_out;

  const int E = in_sizes[1];
  const int nodes_elems = in_sizes[0];               // N * 64
  const int N = nodes_elems / 64;
  const size_t szP = (size_t)nodes_elems * 2;        // bf16 [N,64]
  const size_t need = szP * 2;                       // P + Q

  if (ws_size >= need) {
    unsigned short* P = (unsigned short*)d_ws;
    unsigned short* Q = (unsigned short*)((char*)d_ws + szP);
    const int ntiles = (N + 15) / 16;
    const int pblocks = (ntiles + 3) / 4;
    hipLaunchKernelGGL(node_proj, dim3(pblocks), dim3(256), 0, stream,
                       nodes_emb, W1, P, Q, N);
    hipLaunchKernelGGL(edge_score, dim3(2048), dim3(256), 0, stream,
                       P, Q, src, dst, b1, W2, b2, out, E);
  } else {
    const int epb = TPW * 64;
    const int blocks = (E + epb - 1) / epb;
    hipLaunchKernelGGL(edge_mlp_f32, dim3(blocks), dim3(256), 0, stream,
                       nodes_emb, src, dst, W1, b1, W2, b2, out, E);
  }
}

// Round 10
// 173.704 us; speedup vs baseline: 2.7136x; 1.1737x over previous
//
#include <hip/hip_runtime.h>

// bf16 MFMA fragment types (gfx950): A/B = 8 bf16 (4 VGPR), C/D = 4 fp32
typedef __attribute__((ext_vector_type(8))) short bf16x8;
typedef __attribute__((ext_vector_type(4))) float f32x4;
typedef __attribute__((ext_vector_type(2))) unsigned int u32x2;
typedef __attribute__((ext_vector_type(4))) unsigned int u32x4;

#define LDSTR 136            // W1^T LDS leading dim (shorts): 128 + 8 pad
#define TPW 8                // (fallback) 16-edge tiles per wave

// f32 -> bf16 round-to-nearest-even
static __device__ __forceinline__ unsigned int pack2bf(float x, float y) {
  unsigned int ux = __builtin_bit_cast(unsigned int, x);
  ux += 0x7fffu + ((ux >> 16) & 1u);
  unsigned int uy = __builtin_bit_cast(unsigned int, y);
  uy += 0x7fffu + ((uy >> 16) & 1u);
  return (ux >> 16) | (uy & 0xffff0000u);
}
static __device__ __forceinline__ unsigned short f2bf_s(float x) {
  unsigned int ux = __builtin_bit_cast(unsigned int, x);
  ux += 0x7fffu + ((ux >> 16) & 1u);
  return (unsigned short)(ux >> 16);
}
static __device__ __forceinline__ bf16x8 make_afrag(float4 lo, float4 hi) {
  u32x4 p;
  p[0] = pack2bf(lo.x, lo.y);
  p[1] = pack2bf(lo.z, lo.w);
  p[2] = pack2bf(hi.x, hi.y);
  p[3] = pack2bf(hi.z, hi.w);
  return __builtin_bit_cast(bf16x8, p);
}

// ---- pass 0: per-node projections P = emb@W1[0:64], Q = emb@W1[64:128].
// P/Q rows use PERMUTED channel order: position p holds channel
// ch(p) = (p&3)*16 + (p>>2)  (i.e. pos l15*4+tn <- channel tn*16+l15),
// which makes each lane's 4 accumulator values memory-adjacent ->
// fully-coalesced dwordx2 stores (512 B contiguous per instruction).
// v2 fixes vs r9 (which cost ~110us): W1 staged with COALESCED linear
// reads, grid-stride loop amortizes staging, vector stores (no 2-B scalars).
__global__ __launch_bounds__(256) void node_proj(
    const float* __restrict__ emb,   // [N,64] f32
    const float* __restrict__ W1,    // [128,64] f32 row-major
    u32x2* __restrict__ P,           // [N,16] 8-B units (permuted bf16 rows)
    u32x2* __restrict__ Q,
    int N, int ntiles)
{
  __shared__ unsigned short ls_w1t[64 * LDSTR];   // W1^T [n][k]
  const int tid  = threadIdx.x;
  const int wave = tid >> 6;
  const int lane = tid & 63;
  const int l15  = lane & 15;
  const int quad = lane >> 4;

  // Coalesced staging: consecutive lanes read consecutive W1 elements.
  for (int i = tid; i < 64 * 128; i += 256) {
    int k = i >> 6, n = i & 63;                    // W1[k][n], linear read
    ls_w1t[n * LDSTR + k] = f2bf_s(W1[i]);
  }
  __syncthreads();

  // bfragP[tn][s]: k = s*32+quad*8 (top half); bfragQ: k = 64 + same
  bf16x8 bfragP[4][2], bfragQ[4][2];
  #pragma unroll
  for (int tn = 0; tn < 4; ++tn)
    #pragma unroll
    for (int s = 0; s < 2; ++s) {
      bfragP[tn][s] = *(const bf16x8*)&ls_w1t[(tn * 16 + l15) * LDSTR + s * 32 + quad * 8];
      bfragQ[tn][s] = *(const bf16x8*)&ls_w1t[(tn * 16 + l15) * LDSTR + 64 + s * 32 + quad * 8];
    }

  for (int tile = blockIdx.x * 4 + wave; tile < ntiles; tile += gridDim.x * 4) {
    const int base = tile * 16;

    bf16x8 afr0, afr1;
    {
      int node = base + l15;
      node = (node < N) ? node : N - 1;
      const float* rp = emb + (long long)node * 64 + quad * 8;
      afr0 = make_afrag(*(const float4*)(rp),      *(const float4*)(rp + 4));
      afr1 = make_afrag(*(const float4*)(rp + 32), *(const float4*)(rp + 36));
    }

    f32x4 aP[4], aQ[4];
    #pragma unroll
    for (int tn = 0; tn < 4; ++tn) { aP[tn] = (f32x4){0,0,0,0}; aQ[tn] = (f32x4){0,0,0,0}; }
    #pragma unroll
    for (int tn = 0; tn < 4; ++tn) {
      aP[tn] = __builtin_amdgcn_mfma_f32_16x16x32_bf16(afr0, bfragP[tn][0], aP[tn], 0, 0, 0);
      aQ[tn] = __builtin_amdgcn_mfma_f32_16x16x32_bf16(afr0, bfragQ[tn][0], aQ[tn], 0, 0, 0);
      aP[tn] = __builtin_amdgcn_mfma_f32_16x16x32_bf16(afr1, bfragP[tn][1], aP[tn], 0, 0, 0);
      aQ[tn] = __builtin_amdgcn_mfma_f32_16x16x32_bf16(afr1, bfragQ[tn][1], aQ[tn], 0, 0, 0);
    }

    // Epilogue: row m = base+quad*4+r; lane l15 stores positions l15*4..+3
    // (= its 4 tn values) as one 8-B unit -> 512 B contiguous per instr.
    #pragma unroll
    for (int r = 0; r < 4; ++r) {
      const int m = base + quad * 4 + r;
      if (m < N) {
        u32x2 vp, vq;
        vp[0] = pack2bf(aP[0][r], aP[1][r]);
        vp[1] = pack2bf(aP[2][r], aP[3][r]);
        vq[0] = pack2bf(aQ[0][r], aQ[1][r]);
        vq[1] = pack2bf(aQ[2][r], aQ[3][r]);
        P[(long long)m * 16 + l15] = vp;
        Q[(long long)m * 16 + l15] = vq;
      }
    }
  }
}

// ---- main: pure streaming edge scorer (74us @ r9). 8 lanes per edge, each
// lane holds 8 permuted channels; b1/W2 are looked up through the same
// permutation at setup (channel sum is order-invariant).
__global__ __launch_bounds__(256) void edge_score(
    const unsigned short* __restrict__ P,   // [N,64] bf16 (permuted channels)
    const unsigned short* __restrict__ Q,
    const int*   __restrict__ src,
    const int*   __restrict__ dst,
    const float* __restrict__ b1,    // [64]
    const float* __restrict__ W2,    // [64]
    const float* __restrict__ b2,
    float*       __restrict__ out,   // [E]
    int E)
{
  const int tid  = blockIdx.x * 256 + threadIdx.x;
  const int lane = threadIdx.x & 63;
  const int s    = lane & 7;          // sliver within row (8 bf16 = 16 B)
  const int g    = lane >> 3;         // edge-group within wave (0..7)
  const int wid  = tid >> 6;          // global wave id
  const int nwav = gridDim.x * 4;

  // Channel constants through the storage permutation ch(p)=(p&3)*16+(p>>2)
  float b1v[8], w2v[8];
  #pragma unroll
  for (int j = 0; j < 8; ++j) {
    const int pos = s * 8 + j;
    const int ch  = (pos & 3) * 16 + (pos >> 2);
    b1v[j] = b1[ch];
    w2v[j] = W2[ch];
  }
  const float b2v = b2[0];
  const int so16 = s * 8;             // short offset of this lane's sliver

#define DOT8(PV, QV, ACC)                                                     \
  {                                                                           \
    u32x4 pu = __builtin_bit_cast(u32x4, PV);                                 \
    u32x4 qu = __builtin_bit_cast(u32x4, QV);                                 \
    _Pragma("unroll")                                                         \
    for (int i = 0; i < 4; ++i) {                                             \
      float pl = __builtin_bit_cast(float, pu[i] << 16);                      \
      float ph = __builtin_bit_cast(float, pu[i] & 0xffff0000u);              \
      float ql = __builtin_bit_cast(float, qu[i] << 16);                      \
      float qh = __builtin_bit_cast(float, qu[i] & 0xffff0000u);              \
      float h0 = fmaxf(pl + ql + b1v[2 * i], 0.f);                            \
      float h1 = fmaxf(ph + qh + b1v[2 * i + 1], 0.f);                        \
      ACC = __builtin_fmaf(h0, w2v[2 * i], ACC);                              \
      ACC = __builtin_fmaf(h1, w2v[2 * i + 1], ACC);                          \
    }                                                                         \
  }

  const int step = nwav * 16;
  for (int e0 = wid * 16; e0 < E; e0 += step) {
    int eA = e0 + g;
    int eB = e0 + 8 + g;
    const int eAc = (eA < E) ? eA : (E - 1);
    const int eBc = (eB < E) ? eB : (E - 1);
    const int siA = src[eAc], diA = dst[eAc];
    const int siB = src[eBc], diB = dst[eBc];

    const bf16x8 pvA = *(const bf16x8*)(P + (long long)siA * 64 + so16);
    const bf16x8 qvA = *(const bf16x8*)(Q + (long long)diA * 64 + so16);
    const bf16x8 pvB = *(const bf16x8*)(P + (long long)siB * 64 + so16);
    const bf16x8 qvB = *(const bf16x8*)(Q + (long long)diB * 64 + so16);

    float accA = 0.f, accB = 0.f;
    DOT8(pvA, qvA, accA);
    DOT8(pvB, qvB, accB);

    accA += __shfl_xor(accA, 1); accB += __shfl_xor(accB, 1);
    accA += __shfl_xor(accA, 2); accB += __shfl_xor(accB, 2);
    accA += __shfl_xor(accA, 4); accB += __shfl_xor(accB, 4);

    if (s == 0) {
      if (eA < E) out[eA] = accA + b2v;
      if (eB < E) out[eB] = accB + b2v;
    }
  }
#undef DOT8
}

// ---- fallback: f32 gathers + MFMA (no workspace) ----
__global__ __launch_bounds__(256) void edge_mlp_f32(
    const float* __restrict__ nodes_emb, const int* __restrict__ src,
    const int* __restrict__ dst, const float* __restrict__ W1,
    const float* __restrict__ b1, const float* __restrict__ W2,
    const float* __restrict__ b2, float* __restrict__ out, int E)
{
  __shared__ unsigned short ls_w1t[64 * LDSTR];
  __shared__ float ls_b1[64];
  __shared__ float ls_w2[64];
  const int tid = threadIdx.x, wave = tid >> 6, lane = tid & 63;
  const int l15 = lane & 15, quad = lane >> 4;
  for (int i = tid; i < 64 * 128; i += 256) {
    int n = i >> 7, k = i & 127;
    ls_w1t[n * LDSTR + k] = f2bf_s(W1[k * 64 + n]);
  }
  if (tid < 64) { ls_b1[tid] = b1[tid]; ls_w2[tid] = W2[tid]; }
  __syncthreads();
  bf16x8 bfrag[4][4];
  #pragma unroll
  for (int tn = 0; tn < 4; ++tn)
    #pragma unroll
    for (int s = 0; s < 4; ++s)
      bfrag[tn][s] = *(const bf16x8*)&ls_w1t[(tn * 16 + l15) * LDSTR + s * 32 + quad * 8];
  float myb1[4], myw2[4];
  #pragma unroll
  for (int tn = 0; tn < 4; ++tn) { myb1[tn] = ls_b1[tn*16+l15]; myw2[tn] = ls_w2[tn*16+l15]; }
  const float b2v = b2[0];
  const int wave_base = blockIdx.x * (TPW * 64) + wave * (TPW * 16);
  #pragma unroll 1
  for (int t = 0; t < TPW; ++t) {
    const int tile_base = wave_base + t * 16;
    if (tile_base >= E) break;
    const int e = tile_base + l15;
    const int si = src[e], di = dst[e];
    const float* srow = nodes_emb + (long long)si * 64 + quad * 8;
    const float* drow = nodes_emb + (long long)di * 64 + quad * 8;
    float4 v0 = *(const float4*)(srow),      v1 = *(const float4*)(srow + 4);
    float4 v2 = *(const float4*)(srow + 32), v3 = *(const float4*)(srow + 36);
    float4 v4 = *(const float4*)(drow),      v5 = *(const float4*)(drow + 4);
    float4 v6 = *(const float4*)(drow + 32), v7 = *(const float4*)(drow + 36);
    bf16x8 afr[4] = {make_afrag(v0,v1), make_afrag(v2,v3), make_afrag(v4,v5), make_afrag(v6,v7)};
    f32x4 acc[4];
    #pragma unroll
    for (int tn = 0; tn < 4; ++tn) acc[tn] = (f32x4){0.f,0.f,0.f,0.f};
    #pragma unroll
    for (int s = 0; s < 4; ++s)
      #pragma unroll
      for (int tn = 0; tn < 4; ++tn)
        acc[tn] = __builtin_amdgcn_mfma_f32_16x16x32_bf16(afr[s], bfrag[tn][s], acc[tn], 0, 0, 0);
    #pragma unroll
    for (int r = 0; r < 4; ++r) {
      float p = 0.f;
      #pragma unroll
      for (int tn = 0; tn < 4; ++tn) {
        float h = fmaxf(acc[tn][r] + myb1[tn], 0.f);
        p = __builtin_fmaf(h, myw2[tn], p);
      }
      p += __shfl_xor(p, 1); p += __shfl_xor(p, 2);
      p += __shfl_xor(p, 4); p += __shfl_xor(p, 8);
      if (l15 == 0) out[tile_base + quad * 4 + r] = p + b2v;
    }
  }
}

extern "C" void kernel_launch(void* const* d_in, const int* in_sizes, int n_in,
                              void* d_out, int out_size, void* d_ws, size_t ws_size,
                              hipStream_t stream) {
  const float* nodes_emb = (const float*)d_in[0];
  const int*   src       = (const int*)d_in[1];
  const int*   dst       = (const int*)d_in[2];
  const float* W1        = (const float*)d_in[3];
  const float* b1        = (const float*)d_in[4];
  const float* W2        = (const float*)d_in[5];
  const float* b2        = (const float*)d_in[6];
  float* out = (float*)d_out;

  const int E = in_sizes[1];
  const int nodes_elems = in_sizes[0];               // N * 64
  const int N = nodes_elems / 64;
  const size_t szP = (size_t)nodes_elems * 2;        // bf16 [N,64]
  const size_t need = szP * 2;                       // P + Q

  if (ws_size >= need) {
    u32x2* P = (u32x2*)d_ws;
    u32x2* Q = (u32x2*)((char*)d_ws + szP);
    const int ntiles = (N + 15) / 16;
    hipLaunchKernelGGL(node_proj, dim3(512), dim3(256), 0, stream,
                       nodes_emb, W1, P, Q, N, ntiles);
    hipLaunchKernelGGL(edge_score, dim3(2048), dim3(256), 0, stream,
                       (const unsigned short*)P, (const unsigned short*)Q,
                       src, dst, b1, W2, b2, out, E);
  } else {
    const int epb = TPW * 64;
    const int blocks = (E + epb - 1) / epb;
    hipLaunchKernelGGL(edge_mlp_f32, dim3(blocks), dim3(256), 0, stream,
                       nodes_emb, src, dst, W1, b1, W2, b2, out, E);
  }
}